// Round 1
// baseline (67.495 us; speedup 1.0000x reference)
//
#include <hip/hip_runtime.h>
#include <hip/hip_bf16.h>

#define TT 2048
#define DD 256
#define HH 256

#define GL_DECAY 0.891f        /* DISCOUNT * LAMBDA = 0.99*0.9 */
#define ALPHA    0.01f

// ---------------- workspace layout (floats) ----------------
#define OFF_H   0               /* Hbuf: T x H  = 524288 */
#define OFF_G   524288          /* Gbuf: T x H  = 524288 */
#define OFF_U   1048576         /* u:    T      = 2048   */
#define OFF_C   1050624         /* c:    T      = 2048   */
#define OFF_PW1 1052672         /* partW1: 8 x 65536 = 524288 */
#define OFF_PB1 1576960         /* partB1: 16 x 256 = 4096 */
#define OFF_PW2 1581056         /* partW2: 16 x 256 = 4096 */
#define WS_FLOATS 1585152       /* ~6.05 MB */

// Kernel 1: batched forward. block b -> rows [8b, 8b+8); thread j -> column j.
// A = xs @ W1 + b1 ; H = relu(A); G = (A>0)?W2:0 ; u = H @ W2 + b2
__global__ __launch_bounds__(256) void fwd_kernel(
    const float* __restrict__ xs, const float* __restrict__ W1,
    const float* __restrict__ b1, const float* __restrict__ W2,
    const float* __restrict__ b2,
    float* __restrict__ Hbuf, float* __restrict__ Gbuf, float* __restrict__ u) {
  const int j = threadIdx.x;
  const int r0 = blockIdx.x * 8;
  float bj = b1[j];
  float acc[8];
#pragma unroll
  for (int r = 0; r < 8; ++r) acc[r] = bj;
#pragma unroll 4
  for (int k = 0; k < DD; ++k) {
    float w = W1[k * HH + j];          // coalesced vector load
#pragma unroll
    for (int r = 0; r < 8; ++r)
      acc[r] = fmaf(xs[(r0 + r) * DD + k], w, acc[r]);  // uniform -> scalar load
  }
  float w2j = W2[j];
  __shared__ float red[8][256];
#pragma unroll
  for (int r = 0; r < 8; ++r) {
    float a = acc[r];
    float h = fmaxf(a, 0.0f);
    float g = (a > 0.0f) ? w2j : 0.0f;
    Hbuf[(r0 + r) * HH + j] = h;
    Gbuf[(r0 + r) * HH + j] = g;
    red[r][j] = h * w2j;
  }
  __syncthreads();
  for (int s = 128; s >= 1; s >>= 1) {
    if (j < s) {
#pragma unroll
      for (int r = 0; r < 8; ++r) red[r][j] += red[r][j + s];
    }
    __syncthreads();
  }
  if (j < 8) u[r0 + j] = red[j][0] + b2[0];
}

// Kernel 2: the scalar scans. One block, 256 threads, 8 timesteps/thread.
// Forward:  sigma_t = e_t - r_{t-1};  r_t = keep_t*((1-a)r_{t-1} + a*e_t)
// Backward: c_t = gl*keep_t*c_{t+1} - sigma_t
// Writes c[] to ws; out[66048] = sum(c) (total_b2); out[66049] = sigma_{T-1}.
__global__ __launch_bounds__(256) void scan_kernel(
    const float* __restrict__ u, const float* __restrict__ ys,
    float* __restrict__ c, float* __restrict__ outp) {
  const int t = threadIdx.x;
  const int base = t * 8;
  float e[8], keep[8];
#pragma unroll
  for (int i = 0; i < 8; ++i) {
    float g = ys[(base + i) * 2 + 0];
    float done = ys[(base + i) * 2 + 1];
    float d = g - u[base + i];
    e[i] = d * d;
    keep[i] = (done > 0.5f) ? 0.0f : 1.0f;
  }
  // thread-local composed forward affine
  float A = 1.0f, B = 0.0f;
#pragma unroll
  for (int i = 0; i < 8; ++i) {
    float a = keep[i] * (1.0f - ALPHA);
    float b = keep[i] * (ALPHA * e[i]);
    A = a * A;
    B = a * B + b;
  }
  __shared__ float As[256], Bs[256];
  As[t] = A; Bs[t] = B;
  __syncthreads();
  // inclusive Hillis-Steele scan (left-to-right)
  for (int s = 1; s < 256; s <<= 1) {
    float pA = 1.0f, pB = 0.0f;
    if (t >= s) { pA = As[t - s]; pB = Bs[t - s]; }
    __syncthreads();
    float nA = A * pA;
    float nB = A * pB + B;
    A = nA; B = nB;
    As[t] = A; Bs[t] = B;
    __syncthreads();
  }
  float r = (t == 0) ? 0.0f : Bs[t - 1];   // r entering this chunk (r_init=0)
  float sig[8];
#pragma unroll
  for (int i = 0; i < 8; ++i) {
    sig[i] = e[i] - r;
    float a = keep[i] * (1.0f - ALPHA);
    float b = keep[i] * (ALPHA * e[i]);
    r = a * r + b;
  }
  if (t == 255) outp[66049] = sig[7];      // sigmas[-1]

  // thread-local composed backward affine (process i = 7 .. 0)
  float A2 = 1.0f, B2 = 0.0f;
#pragma unroll
  for (int i = 7; i >= 0; --i) {
    float a = GL_DECAY * keep[i];
    float b = -sig[i];
    float nA = a * A2;
    float nB = a * B2 + b;
    A2 = nA; B2 = nB;
  }
  __syncthreads();
  As[t] = A2; Bs[t] = B2;
  __syncthreads();
  // inclusive scan from the right
  for (int s = 1; s < 256; s <<= 1) {
    float pA = 1.0f, pB = 0.0f;
    if (t + s < 256) { pA = As[t + s]; pB = Bs[t + s]; }
    __syncthreads();
    float nA = A2 * pA;
    float nB = A2 * pB + B2;
    A2 = nA; B2 = nB;
    As[t] = A2; Bs[t] = B2;
    __syncthreads();
  }
  float cin = (t == 255) ? 0.0f : Bs[t + 1];  // c_{base+8}
  float csum = 0.0f;
#pragma unroll
  for (int i = 7; i >= 0; --i) {
    float a = GL_DECAY * keep[i];
    cin = a * cin - sig[i];
    c[base + i] = cin;
    csum += cin;
  }
  __syncthreads();
  As[t] = csum;
  __syncthreads();
  for (int s = 128; s >= 1; s >>= 1) {
    if (t < s) As[t] += As[t + s];
    __syncthreads();
  }
  if (t == 0) outp[66048] = As[0];           // total_b2
}

// Kernel 3: total_W1[d][h] = sum_t xs[t][d] * c[t] * G[t][h]
// grid 256: dc = blockIdx>>3 (32 d-chunks of 8), kc = blockIdx&7 (8 K-chunks of 256)
__global__ __launch_bounds__(256) void w1_kernel(
    const float* __restrict__ xs, const float* __restrict__ G,
    const float* __restrict__ c, float* __restrict__ pW1) {
  const int j = threadIdx.x;
  const int dc = blockIdx.x >> 3;
  const int kc = blockIdx.x & 7;
  const int d0 = dc * 8;
  const int t0 = kc * 256;
  float acc[8];
#pragma unroll
  for (int r = 0; r < 8; ++r) acc[r] = 0.0f;
#pragma unroll 4
  for (int tt = 0; tt < 256; ++tt) {
    const int t = t0 + tt;
    float gc = G[t * HH + j] * c[t];       // vector load * scalar load
#pragma unroll
    for (int r = 0; r < 8; ++r)
      acc[r] = fmaf(gc, xs[t * DD + d0 + r], acc[r]);  // uniform -> scalar
  }
#pragma unroll
  for (int r = 0; r < 8; ++r)
    pW1[kc * 65536 + (d0 + r) * HH + j] = acc[r];
}

// Kernel 4: partial column sums for total_b1 (c*G) and total_W2 (c*H)
__global__ __launch_bounds__(256) void bw_kernel(
    const float* __restrict__ G, const float* __restrict__ Hb,
    const float* __restrict__ c, float* __restrict__ pB1, float* __restrict__ pW2) {
  const int j = threadIdx.x;
  const int s = blockIdx.x;
  float sb = 0.0f, sw = 0.0f;
#pragma unroll 4
  for (int tt = 0; tt < 128; ++tt) {
    const int t = s * 128 + tt;
    float ct = c[t];
    sb = fmaf(ct, G[t * HH + j], sb);
    sw = fmaf(ct, Hb[t * HH + j], sw);
  }
  pB1[s * 256 + j] = sb;
  pW2[s * 256 + j] = sw;
}

// Kernel 5: deterministic reductions into d_out.
// blocks 0..63: W1 (8 partials, float4). block 64: b1 / W2 (16 partials each).
__global__ __launch_bounds__(256) void reduce_kernel(
    const float* __restrict__ pW1, const float* __restrict__ pB1,
    const float* __restrict__ pW2, float* __restrict__ outp) {
  if (blockIdx.x < 64) {
    const int i0 = blockIdx.x * 1024 + threadIdx.x * 4;
    float4 sacc = make_float4(0.f, 0.f, 0.f, 0.f);
#pragma unroll
    for (int k = 0; k < 8; ++k) {
      const float4 v = *reinterpret_cast<const float4*>(pW1 + k * 65536 + i0);
      sacc.x += v.x; sacc.y += v.y; sacc.z += v.z; sacc.w += v.w;
    }
    *reinterpret_cast<float4*>(outp + i0) = sacc;
  } else {
    const int j = threadIdx.x;
    float sb = 0.0f, sw = 0.0f;
#pragma unroll
    for (int k = 0; k < 16; ++k) {
      sb += pB1[k * 256 + j];
      sw += pW2[k * 256 + j];
    }
    outp[65536 + j] = sb;        // total_b1
    outp[65792 + j] = sw;        // total_W2
  }
}

extern "C" void kernel_launch(void* const* d_in, const int* in_sizes, int n_in,
                              void* d_out, int out_size, void* d_ws, size_t ws_size,
                              hipStream_t stream) {
  const float* xs = (const float*)d_in[0];   // (2048, 256)
  const float* ys = (const float*)d_in[1];   // (2048, 2)
  const float* W1 = (const float*)d_in[2];   // (256, 256)
  const float* b1 = (const float*)d_in[3];   // (256,)
  const float* W2 = (const float*)d_in[4];   // (256, 1)
  const float* b2 = (const float*)d_in[5];   // (1,)
  float* outp = (float*)d_out;               // 66050 floats
  float* ws = (float*)d_ws;

  if (ws_size < (size_t)WS_FLOATS * sizeof(float)) return;  // leaves poison -> loud fail

  float* Hbuf = ws + OFF_H;
  float* Gbuf = ws + OFF_G;
  float* ubuf = ws + OFF_U;
  float* cbuf = ws + OFF_C;
  float* pW1  = ws + OFF_PW1;
  float* pB1  = ws + OFF_PB1;
  float* pW2  = ws + OFF_PW2;

  fwd_kernel<<<256, 256, 0, stream>>>(xs, W1, b1, W2, b2, Hbuf, Gbuf, ubuf);
  scan_kernel<<<1, 256, 0, stream>>>(ubuf, ys, cbuf, outp);
  w1_kernel<<<256, 256, 0, stream>>>(xs, Gbuf, cbuf, pW1);
  bw_kernel<<<16, 256, 0, stream>>>(Gbuf, Hbuf, cbuf, pB1, pW2);
  reduce_kernel<<<65, 256, 0, stream>>>(pW1, pB1, pW2, outp);
}